// Round 5
// baseline (87.339 us; speedup 1.0000x reference)
//
#include <hip/hip_runtime.h>
#include <math.h>

#define VOCAB  128000
#define DIM    2048
#define TOPK   50
#define NTHR   512
#define CAP    512
#define NBINS  4096
#define THRESH 3.0f

typedef float f4 __attribute__((ext_vector_type(4)));

__global__ __launch_bounds__(NTHR, 4) void softmix_kernel(
    const float* __restrict__ logits,   // [ROWS, VOCAB]
    const float* __restrict__ emb,      // [VOCAB, DIM]
    float* __restrict__ out)            // [ROWS, DIM]
{
    __shared__ float cand_v[CAP];
    __shared__ int   cand_i[CAP];
    __shared__ unsigned int cand_cnt;
    __shared__ float sel_v[TOPK];
    __shared__ int   sel_i[TOPK];
    __shared__ float sel_w[TOPK];
    __shared__ float wsum;
    // fallback-only storage (unused on the fast path)
    __shared__ unsigned int hist[NBINS];
    __shared__ unsigned int seg[NTHR];
    __shared__ unsigned int binStar;

    const int row = blockIdx.x;
    const int t   = threadIdx.x;
    const f4* lrow = (const f4*)(logits + (size_t)row * VOCAB);
    const int n4 = VOCAB / 4;  // 32000

    if (t == 0) cand_cnt = 0u;
    __syncthreads();

    // ---- single streaming pass, unroll x4: 4 nontemporal loads in flight ----
    // main loop: 15 iters x (4*512) float4 = 30720; remainder loop covers
    // [30720, 32000) with a strided loop (3 iterations of 512 threads).
    #pragma unroll 1
    for (int it = 0; it < 15; ++it) {
        const int p0 = t + it * (4 * NTHR);
        f4 v0 = __builtin_nontemporal_load(lrow + p0);
        f4 v1 = __builtin_nontemporal_load(lrow + p0 + NTHR);
        f4 v2 = __builtin_nontemporal_load(lrow + p0 + 2 * NTHR);
        f4 v3 = __builtin_nontemporal_load(lrow + p0 + 3 * NTHR);
        #pragma unroll
        for (int j = 0; j < 4; ++j) {
            float f = v0[j];
            if (f >= THRESH) {
                unsigned pos = atomicAdd(&cand_cnt, 1u);
                if (pos < CAP) { cand_v[pos] = f; cand_i[pos] = 4 * p0 + j; }
            }
        }
        #pragma unroll
        for (int j = 0; j < 4; ++j) {
            float f = v1[j];
            if (f >= THRESH) {
                unsigned pos = atomicAdd(&cand_cnt, 1u);
                if (pos < CAP) { cand_v[pos] = f; cand_i[pos] = 4 * (p0 + NTHR) + j; }
            }
        }
        #pragma unroll
        for (int j = 0; j < 4; ++j) {
            float f = v2[j];
            if (f >= THRESH) {
                unsigned pos = atomicAdd(&cand_cnt, 1u);
                if (pos < CAP) { cand_v[pos] = f; cand_i[pos] = 4 * (p0 + 2 * NTHR) + j; }
            }
        }
        #pragma unroll
        for (int j = 0; j < 4; ++j) {
            float f = v3[j];
            if (f >= THRESH) {
                unsigned pos = atomicAdd(&cand_cnt, 1u);
                if (pos < CAP) { cand_v[pos] = f; cand_i[pos] = 4 * (p0 + 3 * NTHR) + j; }
            }
        }
    }
    // remainder: float4 indices [30720, 32000), strided — correct for any NTHR
    #pragma unroll 1
    for (int p = 15 * (4 * NTHR) + t; p < n4; p += NTHR) {
        f4 v = __builtin_nontemporal_load(lrow + p);
        #pragma unroll
        for (int j = 0; j < 4; ++j) {
            float f = v[j];
            if (f >= THRESH) {
                unsigned pos = atomicAdd(&cand_cnt, 1u);
                if (pos < CAP) { cand_v[pos] = f; cand_i[pos] = 4 * p + j; }
            }
        }
    }
    __syncthreads();

    int C = (int)cand_cnt;

    // ---- fallback (exact for any input; never taken for N(0,1)) ----
    if (C < TOPK || C > CAP) {
        for (int i = t; i < NBINS; i += NTHR) hist[i] = 0u;
        if (t == 0) cand_cnt = 0u;
        __syncthreads();
        for (int p = t; p < n4; p += NTHR) {
            f4 v = lrow[p];
            #pragma unroll
            for (int j = 0; j < 4; ++j) {
                unsigned u = __float_as_uint(v[j]);
                unsigned key = (u & 0x80000000u) ? ~u : (u | 0x80000000u);
                atomicAdd(&hist[key >> 20], 1u);
            }
        }
        __syncthreads();
        {
            const int per = NBINS / NTHR;  // 8
            const int base = t * per;
            unsigned s = 0;
            for (int i = 0; i < per; ++i) s += hist[base + i];
            seg[t] = s;
            __syncthreads();
            unsigned suff = 0;
            for (int j = NTHR - 1; j > t; --j) suff += seg[j];
            if (suff < TOPK && suff + seg[t] >= TOPK) {
                unsigned running = suff;
                for (int b = per - 1; b >= 0; --b) {
                    unsigned c = hist[base + b];
                    if (running + c >= TOPK) { binStar = (unsigned)(base + b); break; }
                    running += c;
                }
            }
        }
        __syncthreads();
        const unsigned bstar = binStar;
        for (int p = t; p < n4; p += NTHR) {
            f4 v = lrow[p];
            #pragma unroll
            for (int j = 0; j < 4; ++j) {
                float f = v[j];
                unsigned u = __float_as_uint(f);
                unsigned key = (u & 0x80000000u) ? ~u : (u | 0x80000000u);
                if ((key >> 20) >= bstar) {
                    unsigned pos = atomicAdd(&cand_cnt, 1u);
                    if (pos < CAP) { cand_v[pos] = f; cand_i[pos] = 4 * p + j; }
                }
            }
        }
        __syncthreads();
        C = (cand_cnt < (unsigned)CAP) ? (int)cand_cnt : CAP;
    }

    // ---- exact rank selection; tie-break = lower index wins (lax.top_k) ----
    for (int i = t; i < C; i += NTHR) {
        float vi = cand_v[i]; int ii = cand_i[i];
        int rank = 0;
        for (int j = 0; j < C; ++j) {
            float vj = cand_v[j]; int ij = cand_i[j];
            rank += (int)((vj > vi) || (vj == vi && ij < ii));
        }
        if (rank < TOPK) { sel_v[rank] = vi; sel_i[rank] = ii; }
    }
    __syncthreads();

    // ---- weights: exp(v - max); global softmax Z cancels under renorm ----
    if (t < 64) {
        float p = 0.f;
        if (t < TOPK) { p = expf(sel_v[t] - sel_v[0]); sel_w[t] = p; }
        for (int off = 32; off; off >>= 1) p += __shfl_down(p, off);
        if (t == 0) wsum = p;
    }
    __syncthreads();
    const float inv = 1.0f / wsum;

    // ---- gather: dual interleaved chains (k, k+1) widen prefetch window ----
    float4 accA = {0.f, 0.f, 0.f, 0.f};
    float4 accB = {0.f, 0.f, 0.f, 0.f};
    #pragma unroll 1
    for (int k = 0; k < TOPK; k += 2) {
        const float wA = sel_w[k];
        const float wB = sel_w[k + 1];
        const float4* erA = (const float4*)(emb + (size_t)sel_i[k] * DIM);
        const float4* erB = (const float4*)(emb + (size_t)sel_i[k + 1] * DIM);
        float4 eA = erA[t];
        float4 eB = erB[t];
        accA.x += wA * eA.x; accA.y += wA * eA.y; accA.z += wA * eA.z; accA.w += wA * eA.w;
        accB.x += wB * eB.x; accB.y += wB * eB.y; accB.z += wB * eB.z; accB.w += wB * eB.w;
    }
    float4 acc;
    acc.x = (accA.x + accB.x) * inv;
    acc.y = (accA.y + accB.y) * inv;
    acc.z = (accA.z + accB.z) * inv;
    acc.w = (accA.w + accB.w) * inv;

    f4 accv = { acc.x, acc.y, acc.z, acc.w };
    f4* orow = (f4*)(out + (size_t)row * DIM);
    __builtin_nontemporal_store(accv, orow + t);
}

extern "C" void kernel_launch(void* const* d_in, const int* in_sizes, int n_in,
                              void* d_out, int out_size, void* d_ws, size_t ws_size,
                              hipStream_t stream) {
    const float* logits = (const float*)d_in[0];
    const float* emb    = (const float*)d_in[1];
    float* out = (float*)d_out;
    const int rows = in_sizes[0] / VOCAB;   // B*T = 512
    softmix_kernel<<<rows, NTHR, 0, stream>>>(logits, emb, out);
}

// Round 6
// 79.859 us; speedup vs baseline: 1.0937x; 1.0937x over previous
//
#include <hip/hip_runtime.h>
#include <math.h>

#define VOCAB  128000
#define DIM    2048
#define TOPK   50
#define NTHR   1024
#define CAP    512
#define NBINS  4096
#define THRESH 3.0f

typedef float f4 __attribute__((ext_vector_type(4)));

__global__ __launch_bounds__(NTHR, 8) void softmix_kernel(
    const float* __restrict__ logits,   // [ROWS, VOCAB]
    const float* __restrict__ emb,      // [VOCAB, DIM]
    float* __restrict__ out)            // [ROWS, DIM]
{
    __shared__ float cand_v[CAP];
    __shared__ int   cand_i[CAP];
    __shared__ unsigned int cand_cnt;
    __shared__ float sel_v[TOPK];
    __shared__ int   sel_i[TOPK];
    __shared__ float sel_w[TOPK];
    __shared__ float wsum;
    // fallback-only storage; reused as the gather reduction buffer afterwards
    __shared__ unsigned int hist[NBINS];   // 16 KB
    __shared__ unsigned int seg[NTHR];
    __shared__ unsigned int binStar;

    const int row = blockIdx.x;
    const int t   = threadIdx.x;
    const f4* lrow = (const f4*)(logits + (size_t)row * VOCAB);
    const int n4 = VOCAB / 4;  // 32000

    if (t == 0) cand_cnt = 0u;
    __syncthreads();

    // ---- single streaming pass, unroll x4 (4 NT loads in flight) ----
    // main: 7 iters x (4*1024) = 28672 float4s; remainder strided loop.
    #pragma unroll 1
    for (int it = 0; it < 7; ++it) {
        const int p0 = t + it * (4 * NTHR);
        f4 v0 = __builtin_nontemporal_load(lrow + p0);
        f4 v1 = __builtin_nontemporal_load(lrow + p0 + NTHR);
        f4 v2 = __builtin_nontemporal_load(lrow + p0 + 2 * NTHR);
        f4 v3 = __builtin_nontemporal_load(lrow + p0 + 3 * NTHR);
        #pragma unroll
        for (int j = 0; j < 4; ++j) {
            float f = v0[j];
            if (f >= THRESH) {
                unsigned pos = atomicAdd(&cand_cnt, 1u);
                if (pos < CAP) { cand_v[pos] = f; cand_i[pos] = 4 * p0 + j; }
            }
        }
        #pragma unroll
        for (int j = 0; j < 4; ++j) {
            float f = v1[j];
            if (f >= THRESH) {
                unsigned pos = atomicAdd(&cand_cnt, 1u);
                if (pos < CAP) { cand_v[pos] = f; cand_i[pos] = 4 * (p0 + NTHR) + j; }
            }
        }
        #pragma unroll
        for (int j = 0; j < 4; ++j) {
            float f = v2[j];
            if (f >= THRESH) {
                unsigned pos = atomicAdd(&cand_cnt, 1u);
                if (pos < CAP) { cand_v[pos] = f; cand_i[pos] = 4 * (p0 + 2 * NTHR) + j; }
            }
        }
        #pragma unroll
        for (int j = 0; j < 4; ++j) {
            float f = v3[j];
            if (f >= THRESH) {
                unsigned pos = atomicAdd(&cand_cnt, 1u);
                if (pos < CAP) { cand_v[pos] = f; cand_i[pos] = 4 * (p0 + 3 * NTHR) + j; }
            }
        }
    }
    // remainder: float4 indices [28672, 32000), strided — correct for any NTHR
    #pragma unroll 1
    for (int p = 7 * (4 * NTHR) + t; p < n4; p += NTHR) {
        f4 v = __builtin_nontemporal_load(lrow + p);
        #pragma unroll
        for (int j = 0; j < 4; ++j) {
            float f = v[j];
            if (f >= THRESH) {
                unsigned pos = atomicAdd(&cand_cnt, 1u);
                if (pos < CAP) { cand_v[pos] = f; cand_i[pos] = 4 * p + j; }
            }
        }
    }
    __syncthreads();

    int C = (int)cand_cnt;

    // ---- fallback (exact for any input; never taken for N(0,1)) ----
    if (C < TOPK || C > CAP) {
        for (int i = t; i < NBINS; i += NTHR) hist[i] = 0u;
        if (t == 0) cand_cnt = 0u;
        __syncthreads();
        for (int p = t; p < n4; p += NTHR) {
            f4 v = lrow[p];
            #pragma unroll
            for (int j = 0; j < 4; ++j) {
                unsigned u = __float_as_uint(v[j]);
                unsigned key = (u & 0x80000000u) ? ~u : (u | 0x80000000u);
                atomicAdd(&hist[key >> 20], 1u);
            }
        }
        __syncthreads();
        {
            const int per = NBINS / NTHR;  // 4
            const int base = t * per;
            unsigned s = 0;
            for (int i = 0; i < per; ++i) s += hist[base + i];
            seg[t] = s;
            __syncthreads();
            unsigned suff = 0;
            for (int j = NTHR - 1; j > t; --j) suff += seg[j];
            if (suff < TOPK && suff + seg[t] >= TOPK) {
                unsigned running = suff;
                for (int b = per - 1; b >= 0; --b) {
                    unsigned c = hist[base + b];
                    if (running + c >= TOPK) { binStar = (unsigned)(base + b); break; }
                    running += c;
                }
            }
        }
        __syncthreads();
        const unsigned bstar = binStar;
        for (int p = t; p < n4; p += NTHR) {
            f4 v = lrow[p];
            #pragma unroll
            for (int j = 0; j < 4; ++j) {
                float f = v[j];
                unsigned u = __float_as_uint(f);
                unsigned key = (u & 0x80000000u) ? ~u : (u | 0x80000000u);
                if ((key >> 20) >= bstar) {
                    unsigned pos = atomicAdd(&cand_cnt, 1u);
                    if (pos < CAP) { cand_v[pos] = f; cand_i[pos] = 4 * p + j; }
                }
            }
        }
        __syncthreads();
        C = (cand_cnt < (unsigned)CAP) ? (int)cand_cnt : CAP;
    }

    // ---- exact rank selection; tie-break = lower index wins (lax.top_k) ----
    for (int i = t; i < C; i += NTHR) {
        float vi = cand_v[i]; int ii = cand_i[i];
        int rank = 0;
        for (int j = 0; j < C; ++j) {
            float vj = cand_v[j]; int ij = cand_i[j];
            rank += (int)((vj > vi) || (vj == vi && ij < ii));
        }
        if (rank < TOPK) { sel_v[rank] = vi; sel_i[rank] = ii; }
    }
    __syncthreads();

    // ---- weights: exp(v - max); global softmax Z cancels under renorm ----
    if (t < 64) {
        float p = 0.f;
        if (t < TOPK) { p = expf(sel_v[t] - sel_v[0]); sel_w[t] = p; }
        for (int off = 32; off; off >>= 1) p += __shfl_down(p, off);
        if (t == 0) wsum = p;
    }
    __syncthreads();
    const float inv = 1.0f / wsum;

    // ---- gather: block split in two halves, each takes half the k's ----
    // half h handles k-pairs pp = h, h+2, ... (dual chain within the pair);
    // halves combine through LDS (reusing dead hist buffer).
    const int tt   = t & 511;
    const int half = t >> 9;
    float4 accA = {0.f, 0.f, 0.f, 0.f};
    float4 accB = {0.f, 0.f, 0.f, 0.f};
    #pragma unroll 1
    for (int pp = half; pp < TOPK / 2; pp += 2) {
        const int kA = 2 * pp, kB = 2 * pp + 1;
        const float wA = sel_w[kA];
        const float wB = sel_w[kB];
        const float4* erA = (const float4*)(emb + (size_t)sel_i[kA] * DIM);
        const float4* erB = (const float4*)(emb + (size_t)sel_i[kB] * DIM);
        float4 eA = erA[tt];
        float4 eB = erB[tt];
        accA.x += wA * eA.x; accA.y += wA * eA.y; accA.z += wA * eA.z; accA.w += wA * eA.w;
        accB.x += wB * eB.x; accB.y += wB * eB.y; accB.z += wB * eB.z; accB.w += wB * eB.w;
    }
    float4* red = (float4*)hist;   // 512 * 16B = 8 KB <= 16 KB
    if (half == 1) {
        float4 s;
        s.x = accA.x + accB.x; s.y = accA.y + accB.y;
        s.z = accA.z + accB.z; s.w = accA.w + accB.w;
        red[tt] = s;
    }
    __syncthreads();
    if (half == 0) {
        float4 r = red[tt];
        f4 accv;
        accv[0] = (accA.x + accB.x + r.x) * inv;
        accv[1] = (accA.y + accB.y + r.y) * inv;
        accv[2] = (accA.z + accB.z + r.z) * inv;
        accv[3] = (accA.w + accB.w + r.w) * inv;
        f4* orow = (f4*)(out + (size_t)row * DIM);
        __builtin_nontemporal_store(accv, orow + tt);
    }
}

extern "C" void kernel_launch(void* const* d_in, const int* in_sizes, int n_in,
                              void* d_out, int out_size, void* d_ws, size_t ws_size,
                              hipStream_t stream) {
    const float* logits = (const float*)d_in[0];
    const float* emb    = (const float*)d_in[1];
    float* out = (float*)d_out;
    const int rows = in_sizes[0] / VOCAB;   // B*T = 512
    softmix_kernel<<<rows, NTHR, 0, stream>>>(logits, emb, out);
}